// Round 15
// baseline (312.436 us; speedup 1.0000x reference)
//
#include <hip/hip_runtime.h>
#include <hip/hip_bf16.h>

// ---------------------------------------------------------------------------
// Round 15: R13 decomposed into half-site blocks for cross-block overlap.
// 4096 blocks x 512 thr, 64 KiB LDS -> 2 blocks/CU (128-VGPR regime).
// Block (site, half) stages full X and computes 4 heads; per-wave work is
// exactly R13's. Slots live in the freed X region (4 x 16 KB). q/k/v all
// pack to regs (48 total) before X retires -> peak live ~95 < 128.
//   x:(2,1024,64,512) f32  w:(1536,512) f32  pb:(8,64,64) f32  mk:(2,) bool
// ---------------------------------------------------------------------------

typedef __attribute__((ext_vector_type(4))) float f32x4;
typedef __attribute__((ext_vector_type(8))) short s16x8;

#define DIM 512

__device__ __forceinline__ short f2bf(float f) {
    __hip_bfloat16 h = __float2bfloat16(f);
    return __builtin_bit_cast(short, h);
}
__device__ __forceinline__ f32x4 ntld4(const float* p) {
    return __builtin_nontemporal_load((const f32x4*)p);
}
__device__ __forceinline__ void ntst4(float* p, f32x4 v) {
    __builtin_nontemporal_store(v, (f32x4*)p);
}
__device__ __forceinline__ s16x8 pack8(f32x4 a, f32x4 b) {
    s16x8 v;
    v[0] = f2bf(a[0]); v[1] = f2bf(a[1]); v[2] = f2bf(a[2]); v[3] = f2bf(a[3]);
    v[4] = f2bf(b[0]); v[5] = f2bf(b[1]); v[6] = f2bf(b[2]); v[7] = f2bf(b[3]);
    return v;
}
__device__ __forceinline__ int xaddr(int row, int kb) {   // 64x512 bf16, 1KiB rows
    return (row << 10) + (kb ^ ((row & 7) << 4));
}
__device__ __forceinline__ int taddr(int row, int kb) {   // 64x64 bf16, 128B rows
    return (row << 7) + (kb ^ ((row & 7) << 4));
}

// W pre-swizzle: frag chunk idx = (rowblk*16 + ks)*64 + lane -> one 1 KiB
// contiguous read per wave-fragment. q-scale (1/8) folded into Wq rows.
__global__ void conv_w(const float* __restrict__ w, unsigned short* __restrict__ wb) {
    int gid  = blockIdx.x * 256 + threadIdx.x;       // 0 .. 98303
    int lane = gid & 63;
    int ks   = (gid >> 6) & 15;
    int rowblk = gid >> 10;
    int row = rowblk * 16 + (lane & 15);
    int col = ks * 32 + (lane >> 4) * 8;
    const float* p = w + (size_t)row * DIM + col;
    f32x4 a = *(const f32x4*)p;
    f32x4 b = *(const f32x4*)(p + 4);
    float sc = (row < 512) ? 0.125f : 1.0f;
    a *= sc; b *= sc;
    *(s16x8*)(wb + (size_t)gid * 8) = pack8(a, b);
}

template<int WB16>
__device__ __forceinline__ s16x8 wfragL(const unsigned short* __restrict__ wb,
                                        const float* __restrict__ w,
                                        int rowblk, int ks, int lane) {
    if constexpr (WB16) {
        return *(const s16x8*)(wb + ((size_t)(rowblk * 16 + ks) * 64 + lane) * 8);
    } else {
        int row = rowblk * 16 + (lane & 15);
        int col = ks * 32 + (lane >> 4) * 8;
        const float* p = w + (size_t)row * DIM + col;
        f32x4 u0 = *(const f32x4*)p;
        f32x4 u1 = *(const f32x4*)(p + 4);
        float sc = (row < 512) ? 0.125f : 1.0f;
        u0 *= sc; u1 *= sc;
        return pack8(u0, u1);
    }
}

__device__ __forceinline__ bool decode_mask(const unsigned int* mk, int b) {
    unsigned int m0 = mk[0], m1 = mk[1];
    if (m0 <= 1u && m1 <= 1u) return ((b == 0) ? m0 : m1) != 0u;
    return ((const unsigned char*)mk)[b] != 0;
}

#define MFB(a, b, cc) __builtin_amdgcn_mfma_f32_16x16x32_bf16(a, b, cc, 0, 0, 0)

// X fragment reads (4 token-row tiles at K-slice ks) from X region (= smem)
#define XF(ks)                                                               \
    s16x8 af0 = *(const s16x8*)(smem + xaddr(c,      (ks) * 64 + g * 16));   \
    s16x8 af1 = *(const s16x8*)(smem + xaddr(16 + c, (ks) * 64 + g * 16));   \
    s16x8 af2 = *(const s16x8*)(smem + xaddr(32 + c, (ks) * 64 + g * 16));   \
    s16x8 af3 = *(const s16x8*)(smem + xaddr(48 + c, (ks) * 64 + g * 16));

template<int WB16>
__global__ __launch_bounds__(512, 2)
void attn_half(const float* __restrict__ x,
               const float* __restrict__ w,
               const unsigned short* __restrict__ wb,
               const float* __restrict__ pb,
               const unsigned int* __restrict__ mk,
               float* __restrict__ out)
{
    extern __shared__ char smem[];
    const int tid  = threadIdx.x;
    const int lane = tid & 63;
    const int wave = tid >> 6;          // 0..7
    const int g    = lane >> 4;
    const int c    = lane & 15;
    const int h2   = wave >> 1;         // head within half (0..3)
    const int hw2  = wave & 1;          // dh-half (proj) / token-half (attn)
    const int bid  = blockIdx.x;
    const int site = bid >> 1;
    const int half = bid & 1;
    const int gh   = half * 4 + h2;     // global head
    const bool focused = decode_mask(mk, site >> 10);
    const float* xblk   = x   + (size_t)site * (64 * DIM);
    float*       outblk = out + (size_t)site * (64 * DIM);
    const f32x4 zf = {0.f, 0.f, 0.f, 0.f};

    // ---- stage X (R13 pattern, two 32-row groups) ----
    {
        const int row16 = tid >> 4, c16 = tid & 15;
        #pragma unroll
        for (int rr2 = 0; rr2 < 2; ++rr2) {
            const int row = row16 + rr2 * 32;
            const float* gp = xblk + row * DIM;
            #pragma unroll
            for (int j = 0; j < 4; ++j) {
                f32x4 a = ntld4(gp + j * 128 + c16 * 8);
                f32x4 b = ntld4(gp + j * 128 + c16 * 8 + 4);
                *(s16x8*)(smem + xaddr(row, j * 256 + c16 * 16)) = pack8(a, b);
            }
        }
    }
    __syncthreads();                                         // (1) X ready

    if (focused) {
        // ---- out = v = X . Wv^T (eye mask => attn = I) ----
        const int RB = 64 + gh * 4 + 2 * hw2;
        f32x4 va[2][4];
        #pragma unroll
        for (int i = 0; i < 2; ++i)
            #pragma unroll
            for (int j = 0; j < 4; ++j) va[i][j] = zf;
        #pragma unroll 4
        for (int ks = 0; ks < 16; ++ks) {
            s16x8 wv0 = wfragL<WB16>(wb, w, RB,     ks, lane);
            s16x8 wv1 = wfragL<WB16>(wb, w, RB + 1, ks, lane);
            XF(ks)
            va[0][0]=MFB(wv0,af0,va[0][0]); va[0][1]=MFB(wv0,af1,va[0][1]);
            va[0][2]=MFB(wv0,af2,va[0][2]); va[0][3]=MFB(wv0,af3,va[0][3]);
            va[1][0]=MFB(wv1,af0,va[1][0]); va[1][1]=MFB(wv1,af1,va[1][1]);
            va[1][2]=MFB(wv1,af2,va[1][2]); va[1][3]=MFB(wv1,af3,va[1][3]);
        }
        __syncthreads();                 // X reads done -> region = staging
        // stage: row = tok (1KB half-rows), col = local dh
        #pragma unroll
        for (int sub = 0; sub < 2; ++sub)
            #pragma unroll
            for (int tt = 0; tt < 4; ++tt) {
                int rl   = tt * 16 + c;
                int colb = h2 * 256 + hw2 * 128 + sub * 64 + g * 16;
                *(f32x4*)(smem + rl * 1024 + (colb ^ ((rl & 7) << 4))) = va[sub][tt];
            }
        __syncthreads();
        #pragma unroll
        for (int i = 0; i < 8; ++i) {
            int lin = i * 8192 + tid * 16;
            int rl = lin >> 10, off = lin & 1023;
            f32x4 v = *(const f32x4*)(smem + rl * 1024 + (off ^ ((rl & 7) << 4)));
            ntst4((float*)((char*)outblk + rl * 2048 + half * 1024 + off), v);
        }
        return;
    }

    // ===================== full-attention path (4 heads/block) ==============
    const int RQ = gh * 4 + 2 * hw2;
    const int RK = 32 + gh * 4 + 2 * hw2;

    // ---- Q pass (acc 32 regs) -> packed qc (16 regs) ----
    s16x8 qc[4];
    {
        f32x4 acc[4][2];
        #pragma unroll
        for (int t = 0; t < 4; ++t) { acc[t][0] = zf; acc[t][1] = zf; }
        #pragma unroll 4
        for (int ks = 0; ks < 16; ++ks) {
            s16x8 w0 = wfragL<WB16>(wb, w, RQ,     ks, lane);
            s16x8 w1 = wfragL<WB16>(wb, w, RQ + 1, ks, lane);
            XF(ks)
            acc[0][0]=MFB(af0,w0,acc[0][0]); acc[0][1]=MFB(af0,w1,acc[0][1]);
            acc[1][0]=MFB(af1,w0,acc[1][0]); acc[1][1]=MFB(af1,w1,acc[1][1]);
            acc[2][0]=MFB(af2,w0,acc[2][0]); acc[2][1]=MFB(af2,w1,acc[2][1]);
            acc[3][0]=MFB(af3,w0,acc[3][0]); acc[3][1]=MFB(af3,w1,acc[3][1]);
        }
        #pragma unroll
        for (int t = 0; t < 4; ++t) qc[t] = pack8(acc[t][0], acc[t][1]);
    }

    // ---- K pass (acc 32 regs) -> packed kc (16 regs) ----
    s16x8 kc[4];
    {
        f32x4 acc[4][2];
        #pragma unroll
        for (int t = 0; t < 4; ++t) { acc[t][0] = zf; acc[t][1] = zf; }
        #pragma unroll 4
        for (int ks = 0; ks < 16; ++ks) {
            s16x8 w0 = wfragL<WB16>(wb, w, RK,     ks, lane);
            s16x8 w1 = wfragL<WB16>(wb, w, RK + 1, ks, lane);
            XF(ks)
            acc[0][0]=MFB(af0,w0,acc[0][0]); acc[0][1]=MFB(af0,w1,acc[0][1]);
            acc[1][0]=MFB(af1,w0,acc[1][0]); acc[1][1]=MFB(af1,w1,acc[1][1]);
            acc[2][0]=MFB(af2,w0,acc[2][0]); acc[2][1]=MFB(af2,w1,acc[2][1]);
            acc[3][0]=MFB(af3,w0,acc[3][0]); acc[3][1]=MFB(af3,w1,acc[3][1]);
        }
        #pragma unroll
        for (int t = 0; t < 4; ++t) kc[t] = pack8(acc[t][0], acc[t][1]);
    }

    // ---- V pass as vT, two 1-rowblk sub-passes (acc 16 regs) ----
    s16x8 vc[4];
    #pragma unroll
    for (int sub = 0; sub < 2; ++sub) {
        const int RB = 64 + gh * 4 + 2 * hw2 + sub;
        f32x4 a0 = zf, a1 = zf, a2 = zf, a3 = zf;
        #pragma unroll 4
        for (int ks = 0; ks < 16; ++ks) {
            s16x8 wv = wfragL<WB16>(wb, w, RB, ks, lane);
            XF(ks)
            a0 = MFB(wv, af0, a0); a1 = MFB(wv, af1, a1);
            a2 = MFB(wv, af2, a2); a3 = MFB(wv, af3, a3);
        }
        vc[sub * 2]     = pack8(a0, a1);
        vc[sub * 2 + 1] = pack8(a2, a3);
    }

    __syncthreads();                     // (2) X dead -> 4 x 16KB head slots

    char* slotA = smem + h2 * 16384;     // k -> attn
    char* slotB = slotA + 8192;          // q -> vT

    // ---- q -> slotB, k -> slotA (qc, kc die) ----
    #pragma unroll
    for (int t = 0; t < 4; ++t)
        #pragma unroll
        for (int hc = 0; hc < 2; ++hc)
            #pragma unroll
            for (int rr = 0; rr < 4; ++rr) {
                int row = t * 16 + g * 4 + rr;
                int col = hw2 * 32 + hc * 16 + c;
                int off = (row << 7) + ((col * 2) ^ ((row & 7) << 4));
                *(short*)(slotB + off) = qc[t][hc * 4 + rr];
                *(short*)(slotA + off) = kc[t][hc * 4 + rr];
            }
    __syncthreads();                     // (3) q,k visible

    // ---- pre-read q A-frags (16 regs), then retire vT over q ----
    s16x8 qf[2][2];
    #pragma unroll
    for (int ks2 = 0; ks2 < 2; ++ks2)
        #pragma unroll
        for (int tr2 = 0; tr2 < 2; ++tr2)
            qf[ks2][tr2] = *(const s16x8*)(slotB +
                taddr((2 * hw2 + tr2) * 16 + c, ks2 * 64 + g * 16));
    __syncthreads();                     // (3b) q reads done

    #pragma unroll
    for (int sub = 0; sub < 2; ++sub)
        #pragma unroll
        for (int t = 0; t < 4; ++t)
            #pragma unroll
            for (int rr = 0; rr < 4; ++rr) {
                int row = hw2 * 32 + sub * 16 + g * 4 + rr;
                int col = t * 16 + c;
                *(short*)(slotB + (row << 7) + ((col * 2) ^ ((row & 7) << 4))) =
                    vc[sub * 2 + (t >> 1)][(t & 1) * 4 + rr];
            }

    // ---- sim = q . k^T (q from regs, k from slotA) ----
    f32x4 sm[2][4];
    #pragma unroll
    for (int i = 0; i < 2; ++i)
        #pragma unroll
        for (int j = 0; j < 4; ++j) sm[i][j] = zf;
    #pragma unroll
    for (int ks2 = 0; ks2 < 2; ++ks2) {
        #pragma unroll
        for (int j = 0; j < 4; ++j) {
            s16x8 bk = *(const s16x8*)(slotA + taddr(j * 16 + c, ks2 * 64 + g * 16));
            sm[0][j] = MFB(qf[ks2][0], bk, sm[0][j]);
            sm[1][j] = MFB(qf[ks2][1], bk, sm[1][j]);
        }
    }

    // ---- bias + softmax ----
    const float* pbh = pb + gh * 4096;
    #pragma unroll
    for (int tr = 0; tr < 2; ++tr) {
        #pragma unroll
        for (int rr = 0; rr < 4; ++rr) {
            const int i = 32 * hw2 + tr * 16 + g * 4 + rr;
            float v0 = sm[tr][0][rr] + pbh[i * 64 +  0 + c];
            float v1 = sm[tr][1][rr] + pbh[i * 64 + 16 + c];
            float v2 = sm[tr][2][rr] + pbh[i * 64 + 32 + c];
            float v3 = sm[tr][3][rr] + pbh[i * 64 + 48 + c];
            float mx = fmaxf(fmaxf(v0, v1), fmaxf(v2, v3));
            mx = fmaxf(mx, __shfl_xor(mx, 1));
            mx = fmaxf(mx, __shfl_xor(mx, 2));
            mx = fmaxf(mx, __shfl_xor(mx, 4));
            mx = fmaxf(mx, __shfl_xor(mx, 8));
            float p0 = __expf(v0 - mx);
            float p1 = __expf(v1 - mx);
            float p2 = __expf(v2 - mx);
            float p3 = __expf(v3 - mx);
            float ssum = p0 + p1 + p2 + p3;
            ssum += __shfl_xor(ssum, 1);
            ssum += __shfl_xor(ssum, 2);
            ssum += __shfl_xor(ssum, 4);
            ssum += __shfl_xor(ssum, 8);
            float rinv = 1.0f / ssum;
            sm[tr][0][rr] = p0 * rinv; sm[tr][1][rr] = p1 * rinv;
            sm[tr][2][rr] = p2 * rinv; sm[tr][3][rr] = p3 * rinv;
        }
    }
    __syncthreads();                     // (4) k reads done

    // ---- attn -> slotA (own token-half rows) ----
    #pragma unroll
    for (int tr = 0; tr < 2; ++tr)
        #pragma unroll
        for (int tc = 0; tc < 4; ++tc)
            #pragma unroll
            for (int rr = 0; rr < 4; ++rr) {
                int row = 32 * hw2 + tr * 16 + g * 4 + rr;
                int col = tc * 16 + c;
                *(short*)(slotA + (row << 7) + ((col * 2) ^ ((row & 7) << 4))) =
                    f2bf(sm[tr][tc][rr]);
            }
    __syncthreads();                     // (5) attn, vT visible

    // ---- PV: oT = vT . attn^T ----
    f32x4 ot[4][2];
    #pragma unroll
    for (int i = 0; i < 4; ++i) { ot[i][0] = zf; ot[i][1] = zf; }
    #pragma unroll
    for (int ks2 = 0; ks2 < 2; ++ks2) {
        s16x8 ba0 = *(const s16x8*)(slotA + taddr((2 * hw2 + 0) * 16 + c, ks2 * 64 + g * 16));
        s16x8 ba1 = *(const s16x8*)(slotA + taddr((2 * hw2 + 1) * 16 + c, ks2 * 64 + g * 16));
        #pragma unroll
        for (int i = 0; i < 4; ++i) {
            s16x8 av = *(const s16x8*)(slotB + taddr(i * 16 + c, ks2 * 64 + g * 16));
            ot[i][0] = MFB(av, ba0, ot[i][0]);
            ot[i][1] = MFB(av, ba1, ot[i][1]);
        }
    }
    __syncthreads();                     // (6) slots dead -> staging

    // ---- staged linear epilogue (64 x 1KB half-rows) ----
    #pragma unroll
    for (int i = 0; i < 4; ++i)
        #pragma unroll
        for (int j = 0; j < 2; ++j) {
            int rl   = 32 * hw2 + j * 16 + c;                // token row
            int colb = h2 * 256 + i * 64 + g * 16;           // local dh bytes
            *(f32x4*)(smem + rl * 1024 + (colb ^ ((rl & 7) << 4))) = ot[i][j];
        }
    __syncthreads();                     // (7)
    #pragma unroll
    for (int i = 0; i < 8; ++i) {
        int lin = i * 8192 + tid * 16;
        int rl = lin >> 10, off = lin & 1023;
        f32x4 v = *(const f32x4*)(smem + rl * 1024 + (off ^ ((rl & 7) << 4)));
        ntst4((float*)((char*)outblk + rl * 2048 + half * 1024 + off), v);
    }
}

extern "C" void kernel_launch(void* const* d_in, const int* in_sizes, int n_in,
                              void* d_out, int out_size, void* d_ws, size_t ws_size,
                              hipStream_t stream)
{
    const float* x  = (const float*)d_in[0];
    const float* w  = (const float*)d_in[1];
    const float* pb = (const float*)d_in[2];
    const unsigned int* mk = (const unsigned int*)d_in[3];
    float* out = (float*)d_out;

    const int LDS = 65536;
    const size_t wbytes = (size_t)1536 * 512 * sizeof(unsigned short);

    if (ws_size >= wbytes) {
        unsigned short* wbp = (unsigned short*)d_ws;
        conv_w<<<dim3(384), dim3(256), 0, stream>>>(w, wbp);
        hipFuncSetAttribute(reinterpret_cast<const void*>(&attn_half<1>),
                            hipFuncAttributeMaxDynamicSharedMemorySize, LDS);
        attn_half<1><<<dim3(4096), dim3(512), LDS, stream>>>(x, w, wbp, pb, mk, out);
    } else {
        hipFuncSetAttribute(reinterpret_cast<const void*>(&attn_half<0>),
                            hipFuncAttributeMaxDynamicSharedMemorySize, LDS);
        attn_half<0><<<dim3(4096), dim3(512), LDS, stream>>>(x, w, nullptr, pb, mk, out);
    }
}

// Round 16
// 277.955 us; speedup vs baseline: 1.1241x; 1.1241x over previous
//
#include <hip/hip_runtime.h>
#include <hip/hip_bf16.h>

// ---------------------------------------------------------------------------
// Round 16: R13 champion (275us) minus the redundant barrier (3b).
// The q A-frag pre-read and the vT retire-write touch the SAME rows from the
// SAME wave (DS ops in-order within a wave); cross-wave row ranges are
// disjoint (hw2=0: rows 0-31, hw2=1: rows 32-63). Barriers 8 -> 7.
//   x:(2,1024,64,512) f32  w:(1536,512) f32  pb:(8,64,64) f32  mk:(2,) bool
// ---------------------------------------------------------------------------

typedef __attribute__((ext_vector_type(4))) float f32x4;
typedef __attribute__((ext_vector_type(8))) short s16x8;

#define DIM 512

__device__ __forceinline__ short f2bf(float f) {
    __hip_bfloat16 h = __float2bfloat16(f);
    return __builtin_bit_cast(short, h);
}
__device__ __forceinline__ f32x4 ntld4(const float* p) {
    return __builtin_nontemporal_load((const f32x4*)p);
}
__device__ __forceinline__ void ntst4(float* p, f32x4 v) {
    __builtin_nontemporal_store(v, (f32x4*)p);
}
__device__ __forceinline__ s16x8 pack8(f32x4 a, f32x4 b) {
    s16x8 v;
    v[0] = f2bf(a[0]); v[1] = f2bf(a[1]); v[2] = f2bf(a[2]); v[3] = f2bf(a[3]);
    v[4] = f2bf(b[0]); v[5] = f2bf(b[1]); v[6] = f2bf(b[2]); v[7] = f2bf(b[3]);
    return v;
}
__device__ __forceinline__ int xaddr(int row, int kb) {   // 64x512 bf16, 1KiB rows
    return (row << 10) + (kb ^ ((row & 7) << 4));
}
__device__ __forceinline__ int taddr(int row, int kb) {   // 64x64 bf16, 128B rows
    return (row << 7) + (kb ^ ((row & 7) << 4));
}

// W pre-swizzle: frag chunk idx = (rowblk*16 + ks)*64 + lane -> one 1 KiB
// contiguous read per wave-fragment. q-scale (1/8) folded into Wq rows.
__global__ void conv_w(const float* __restrict__ w, unsigned short* __restrict__ wb) {
    int gid  = blockIdx.x * 256 + threadIdx.x;       // 0 .. 98303
    int lane = gid & 63;
    int ks   = (gid >> 6) & 15;
    int rowblk = gid >> 10;
    int row = rowblk * 16 + (lane & 15);
    int col = ks * 32 + (lane >> 4) * 8;
    const float* p = w + (size_t)row * DIM + col;
    f32x4 a = *(const f32x4*)p;
    f32x4 b = *(const f32x4*)(p + 4);
    float sc = (row < 512) ? 0.125f : 1.0f;
    a *= sc; b *= sc;
    *(s16x8*)(wb + (size_t)gid * 8) = pack8(a, b);
}

template<int WB16>
__device__ __forceinline__ s16x8 wfragL(const unsigned short* __restrict__ wb,
                                        const float* __restrict__ w,
                                        int rowblk, int ks, int lane) {
    if constexpr (WB16) {
        return *(const s16x8*)(wb + ((size_t)(rowblk * 16 + ks) * 64 + lane) * 8);
    } else {
        int row = rowblk * 16 + (lane & 15);
        int col = ks * 32 + (lane >> 4) * 8;
        const float* p = w + (size_t)row * DIM + col;
        f32x4 u0 = *(const f32x4*)p;
        f32x4 u1 = *(const f32x4*)(p + 4);
        float sc = (row < 512) ? 0.125f : 1.0f;
        u0 *= sc; u1 *= sc;
        return pack8(u0, u1);
    }
}

__device__ __forceinline__ bool decode_mask(const unsigned int* mk, int b) {
    unsigned int m0 = mk[0], m1 = mk[1];
    if (m0 <= 1u && m1 <= 1u) return ((b == 0) ? m0 : m1) != 0u;
    return ((const unsigned char*)mk)[b] != 0;
}

#define MFB(a, b, cc) __builtin_amdgcn_mfma_f32_16x16x32_bf16(a, b, cc, 0, 0, 0)

// X fragment reads (4 token-row tiles at K-slice ks) from region A (= smem)
#define XF(ks)                                                               \
    s16x8 af0 = *(const s16x8*)(smem + xaddr(c,      (ks) * 64 + g * 16));   \
    s16x8 af1 = *(const s16x8*)(smem + xaddr(16 + c, (ks) * 64 + g * 16));   \
    s16x8 af2 = *(const s16x8*)(smem + xaddr(32 + c, (ks) * 64 + g * 16));   \
    s16x8 af3 = *(const s16x8*)(smem + xaddr(48 + c, (ks) * 64 + g * 16));

template<int WB16>
__global__ __launch_bounds__(1024, 4)
void attn_merged(const float* __restrict__ x,
                 const float* __restrict__ w,
                 const unsigned short* __restrict__ wb,
                 const float* __restrict__ pb,
                 const unsigned int* __restrict__ mk,
                 float* __restrict__ out)
{
    extern __shared__ char smem[];
    const int tid  = threadIdx.x;
    const int lane = tid & 63;
    const int wave = tid >> 6;          // 0..15
    const int g    = lane >> 4;
    const int c    = lane & 15;
    const int hp   = wave >> 1;         // head
    const int hw2  = wave & 1;          // dh-half (proj) / token-half (attn)
    const int site = blockIdx.x;
    const bool focused = decode_mask(mk, site >> 10);
    const float* xblk   = x   + (size_t)site * (64 * DIM);
    float*       outblk = out + (size_t)site * (64 * DIM);
    const f32x4 zf = {0.f, 0.f, 0.f, 0.f};

    // ---- stage X: conflict-free (16-lane groups write 256B contiguous) ----
    {
        const int row = tid >> 4, c16 = tid & 15;
        const float* gp = xblk + row * DIM;
        #pragma unroll
        for (int j = 0; j < 4; ++j) {
            f32x4 a = ntld4(gp + j * 128 + c16 * 8);
            f32x4 b = ntld4(gp + j * 128 + c16 * 8 + 4);
            *(s16x8*)(smem + xaddr(row, j * 256 + c16 * 16)) = pack8(a, b);
        }
    }
    __syncthreads();                                         // (1) X ready

    if (focused) {
        // ---------- out = v = X . Wv^T (eye mask => attn = I) ----------
        const int RB = 64 + hp * 4 + 2 * hw2;
        f32x4 va[2][4];
        #pragma unroll
        for (int i = 0; i < 2; ++i)
            #pragma unroll
            for (int j = 0; j < 4; ++j) va[i][j] = zf;
        #pragma unroll 4
        for (int ks = 0; ks < 16; ++ks) {
            s16x8 wv0 = wfragL<WB16>(wb, w, RB,     ks, lane);
            s16x8 wv1 = wfragL<WB16>(wb, w, RB + 1, ks, lane);
            XF(ks)
            va[0][0]=MFB(wv0,af0,va[0][0]); va[0][1]=MFB(wv0,af1,va[0][1]);
            va[0][2]=MFB(wv0,af2,va[0][2]); va[0][3]=MFB(wv0,af3,va[0][3]);
            va[1][0]=MFB(wv1,af0,va[1][0]); va[1][1]=MFB(wv1,af1,va[1][1]);
            va[1][2]=MFB(wv1,af2,va[1][2]); va[1][3]=MFB(wv1,af3,va[1][3]);
        }
        // staged linear epilogue, two 32-row halves in region B
        char* stg = smem + 65536;
        #pragma unroll
        for (int h2 = 0; h2 < 2; ++h2) {
            #pragma unroll
            for (int sub = 0; sub < 2; ++sub)
                #pragma unroll
                for (int tn = 0; tn < 2; ++tn) {
                    int rl   = tn * 16 + c;                  // local token row
                    int colb = hp * 256 + hw2 * 128 + sub * 64 + g * 16;
                    *(f32x4*)(stg + rl * 2048 + (colb ^ ((rl & 7) << 4))) =
                        va[sub][h2 * 2 + tn];
                }
            __syncthreads();
            #pragma unroll
            for (int i = 0; i < 4; ++i) {
                int lin = i * 16384 + tid * 16;
                int rl = lin >> 11, off = lin & 2047;
                f32x4 v = *(const f32x4*)(stg + rl * 2048 + (off ^ ((rl & 7) << 4)));
                ntst4((float*)((char*)outblk + h2 * 65536 + lin), v);
            }
            if (h2 == 0) __syncthreads();
        }
        return;
    }

    // ===================== full-attention path =====================
    char* slotA = smem + hp * 8192;             // (X) -> k -> attn
    char* slotB = smem + 65536 + hp * 8192;     // q -> vT
    const int RQ = hp * 4 + 2 * hw2;
    const int RK = 32 + hp * 4 + 2 * hw2;

    // ---- Q pass (acc 32 regs) -> q tile straight to slotB ----
    {
        f32x4 acc[4][2];
        #pragma unroll
        for (int t = 0; t < 4; ++t) { acc[t][0] = zf; acc[t][1] = zf; }
        #pragma unroll 4
        for (int ks = 0; ks < 16; ++ks) {
            s16x8 w0 = wfragL<WB16>(wb, w, RQ,     ks, lane);
            s16x8 w1 = wfragL<WB16>(wb, w, RQ + 1, ks, lane);
            XF(ks)
            acc[0][0]=MFB(af0,w0,acc[0][0]); acc[0][1]=MFB(af0,w1,acc[0][1]);
            acc[1][0]=MFB(af1,w0,acc[1][0]); acc[1][1]=MFB(af1,w1,acc[1][1]);
            acc[2][0]=MFB(af2,w0,acc[2][0]); acc[2][1]=MFB(af2,w1,acc[2][1]);
            acc[3][0]=MFB(af3,w0,acc[3][0]); acc[3][1]=MFB(af3,w1,acc[3][1]);
        }
        #pragma unroll
        for (int t = 0; t < 4; ++t)
            #pragma unroll
            for (int hc = 0; hc < 2; ++hc)
                #pragma unroll
                for (int rr = 0; rr < 4; ++rr) {
                    int row = t * 16 + g * 4 + rr;
                    int col = hw2 * 32 + hc * 16 + c;
                    *(short*)(slotB + (row << 7) + ((col * 2) ^ ((row & 7) << 4))) =
                        f2bf(acc[t][hc][rr]);
                }
    }

    // ---- K pass (acc 32 regs) -> packed kc (16 regs) ----
    s16x8 kc[4];
    {
        f32x4 acc[4][2];
        #pragma unroll
        for (int t = 0; t < 4; ++t) { acc[t][0] = zf; acc[t][1] = zf; }
        #pragma unroll 4
        for (int ks = 0; ks < 16; ++ks) {
            s16x8 w0 = wfragL<WB16>(wb, w, RK,     ks, lane);
            s16x8 w1 = wfragL<WB16>(wb, w, RK + 1, ks, lane);
            XF(ks)
            acc[0][0]=MFB(af0,w0,acc[0][0]); acc[0][1]=MFB(af0,w1,acc[0][1]);
            acc[1][0]=MFB(af1,w0,acc[1][0]); acc[1][1]=MFB(af1,w1,acc[1][1]);
            acc[2][0]=MFB(af2,w0,acc[2][0]); acc[2][1]=MFB(af2,w1,acc[2][1]);
            acc[3][0]=MFB(af3,w0,acc[3][0]); acc[3][1]=MFB(af3,w1,acc[3][1]);
        }
        #pragma unroll
        for (int t = 0; t < 4; ++t) kc[t] = pack8(acc[t][0], acc[t][1]);
    }

    // ---- V pass as vT, two 1-rowblk sub-passes (acc 16 regs) ----
    s16x8 vc[4];
    #pragma unroll
    for (int sub = 0; sub < 2; ++sub) {
        const int RB = 64 + hp * 4 + 2 * hw2 + sub;
        f32x4 a0 = zf, a1 = zf, a2 = zf, a3 = zf;
        #pragma unroll 4
        for (int ks = 0; ks < 16; ++ks) {
            s16x8 wv = wfragL<WB16>(wb, w, RB, ks, lane);
            XF(ks)
            a0 = MFB(wv, af0, a0); a1 = MFB(wv, af1, a1);
            a2 = MFB(wv, af2, a2); a3 = MFB(wv, af3, a3);
        }
        vc[sub * 2]     = pack8(a0, a1);
        vc[sub * 2 + 1] = pack8(a2, a3);
    }

    __syncthreads();                                         // (2) X dead -> slots

    // ---- k -> slotA ----
    #pragma unroll
    for (int t = 0; t < 4; ++t)
        #pragma unroll
        for (int hc = 0; hc < 2; ++hc)
            #pragma unroll
            for (int rr = 0; rr < 4; ++rr) {
                int row = t * 16 + g * 4 + rr;
                int col = hw2 * 32 + hc * 16 + c;
                *(short*)(slotA + (row << 7) + ((col * 2) ^ ((row & 7) << 4))) =
                    kc[t][hc * 4 + rr];
            }
    __syncthreads();                                         // (3) q,k visible

    // ---- pre-read q A-frags into registers (16 regs), then retire vT ----
    // No barrier needed: reads and the following writes touch the same rows
    // from the SAME wave (DS ops are in-order within a wave); the partner
    // wave's rows are disjoint (hw2=0: rows 0-31, hw2=1: rows 32-63).
    s16x8 qf[2][2];
    #pragma unroll
    for (int ks2 = 0; ks2 < 2; ++ks2)
        #pragma unroll
        for (int tr2 = 0; tr2 < 2; ++tr2)
            qf[ks2][tr2] = *(const s16x8*)(slotB +
                taddr((2 * hw2 + tr2) * 16 + c, ks2 * 64 + g * 16));

    // vT -> slotB (own dh-half rows); vc dies here, before sim
    #pragma unroll
    for (int sub = 0; sub < 2; ++sub)
        #pragma unroll
        for (int t = 0; t < 4; ++t)
            #pragma unroll
            for (int rr = 0; rr < 4; ++rr) {
                int row = hw2 * 32 + sub * 16 + g * 4 + rr;
                int col = t * 16 + c;
                *(short*)(slotB + (row << 7) + ((col * 2) ^ ((row & 7) << 4))) =
                    vc[sub * 2 + (t >> 1)][(t & 1) * 4 + rr];
            }

    // ---- sim = q . k^T (q from regs, k from slotA, sequenced) ----
    f32x4 sm[2][4];
    #pragma unroll
    for (int i = 0; i < 2; ++i)
        #pragma unroll
        for (int j = 0; j < 4; ++j) sm[i][j] = zf;
    #pragma unroll
    for (int ks2 = 0; ks2 < 2; ++ks2) {
        #pragma unroll
        for (int j = 0; j < 4; ++j) {
            s16x8 bk = *(const s16x8*)(slotA + taddr(j * 16 + c, ks2 * 64 + g * 16));
            sm[0][j] = MFB(qf[ks2][0], bk, sm[0][j]);
            sm[1][j] = MFB(qf[ks2][1], bk, sm[1][j]);
        }
    }

    // ---- bias + softmax ----
    const float* pbh = pb + hp * 4096;
    #pragma unroll
    for (int tr = 0; tr < 2; ++tr) {
        #pragma unroll
        for (int rr = 0; rr < 4; ++rr) {
            const int i = 32 * hw2 + tr * 16 + g * 4 + rr;
            float v0 = sm[tr][0][rr] + pbh[i * 64 +  0 + c];
            float v1 = sm[tr][1][rr] + pbh[i * 64 + 16 + c];
            float v2 = sm[tr][2][rr] + pbh[i * 64 + 32 + c];
            float v3 = sm[tr][3][rr] + pbh[i * 64 + 48 + c];
            float mx = fmaxf(fmaxf(v0, v1), fmaxf(v2, v3));
            mx = fmaxf(mx, __shfl_xor(mx, 1));
            mx = fmaxf(mx, __shfl_xor(mx, 2));
            mx = fmaxf(mx, __shfl_xor(mx, 4));
            mx = fmaxf(mx, __shfl_xor(mx, 8));
            float p0 = __expf(v0 - mx);
            float p1 = __expf(v1 - mx);
            float p2 = __expf(v2 - mx);
            float p3 = __expf(v3 - mx);
            float ssum = p0 + p1 + p2 + p3;
            ssum += __shfl_xor(ssum, 1);
            ssum += __shfl_xor(ssum, 2);
            ssum += __shfl_xor(ssum, 4);
            ssum += __shfl_xor(ssum, 8);
            float rinv = 1.0f / ssum;
            sm[tr][0][rr] = p0 * rinv; sm[tr][1][rr] = p1 * rinv;
            sm[tr][2][rr] = p2 * rinv; sm[tr][3][rr] = p3 * rinv;
        }
    }
    __syncthreads();                                         // (4) k reads done

    // ---- attn -> slotA (own token-half rows) ----
    #pragma unroll
    for (int tr = 0; tr < 2; ++tr)
        #pragma unroll
        for (int tc = 0; tc < 4; ++tc)
            #pragma unroll
            for (int rr = 0; rr < 4; ++rr) {
                int row = 32 * hw2 + tr * 16 + g * 4 + rr;
                int col = tc * 16 + c;
                *(short*)(slotA + (row << 7) + ((col * 2) ^ ((row & 7) << 4))) =
                    f2bf(sm[tr][tc][rr]);
            }
    __syncthreads();                                         // (5) attn visible

    // ---- PV: oT = vT . attn^T (token-split cols), frags sequenced ----
    f32x4 ot[4][2];
    #pragma unroll
    for (int i = 0; i < 4; ++i) { ot[i][0] = zf; ot[i][1] = zf; }
    #pragma unroll
    for (int ks2 = 0; ks2 < 2; ++ks2) {
        s16x8 ba0 = *(const s16x8*)(slotA + taddr((2 * hw2 + 0) * 16 + c, ks2 * 64 + g * 16));
        s16x8 ba1 = *(const s16x8*)(slotA + taddr((2 * hw2 + 1) * 16 + c, ks2 * 64 + g * 16));
        #pragma unroll
        for (int i = 0; i < 4; ++i) {
            s16x8 av = *(const s16x8*)(slotB + taddr(i * 16 + c, ks2 * 64 + g * 16));
            ot[i][0] = MFB(av, ba0, ot[i][0]);
            ot[i][1] = MFB(av, ba1, ot[i][1]);
        }
    }
    __syncthreads();                                         // (6) slots dead

    // ---- staged linear epilogue over full 128 KiB ----
    #pragma unroll
    for (int i = 0; i < 4; ++i)
        #pragma unroll
        for (int j = 0; j < 2; ++j) {
            int rl   = 32 * hw2 + j * 16 + c;                // token row
            int colb = hp * 256 + i * 64 + g * 16;           // dh byte offset
            *(f32x4*)(smem + rl * 2048 + (colb ^ ((rl & 7) << 4))) = ot[i][j];
        }
    __syncthreads();                                         // (7)
    #pragma unroll
    for (int i = 0; i < 8; ++i) {
        int lin = i * 16384 + tid * 16;
        int rl = lin >> 11, off = lin & 2047;
        f32x4 v = *(const f32x4*)(smem + rl * 2048 + (off ^ ((rl & 7) << 4)));
        ntst4((float*)((char*)outblk + lin), v);
    }
}

extern "C" void kernel_launch(void* const* d_in, const int* in_sizes, int n_in,
                              void* d_out, int out_size, void* d_ws, size_t ws_size,
                              hipStream_t stream)
{
    const float* x  = (const float*)d_in[0];
    const float* w  = (const float*)d_in[1];
    const float* pb = (const float*)d_in[2];
    const unsigned int* mk = (const unsigned int*)d_in[3];
    float* out = (float*)d_out;

    const int LDS = 131072;
    const size_t wbytes = (size_t)1536 * 512 * sizeof(unsigned short);

    if (ws_size >= wbytes) {
        unsigned short* wbp = (unsigned short*)d_ws;
        conv_w<<<dim3(384), dim3(256), 0, stream>>>(w, wbp);
        hipFuncSetAttribute(reinterpret_cast<const void*>(&attn_merged<1>),
                            hipFuncAttributeMaxDynamicSharedMemorySize, LDS);
        attn_merged<1><<<dim3(2048), dim3(1024), LDS, stream>>>(x, w, wbp, pb, mk, out);
    } else {
        hipFuncSetAttribute(reinterpret_cast<const void*>(&attn_merged<0>),
                            hipFuncAttributeMaxDynamicSharedMemorySize, LDS);
        attn_merged<0><<<dim3(2048), dim3(1024), LDS, stream>>>(x, w, nullptr, pb, mk, out);
    }
}

// Round 17
// 274.677 us; speedup vs baseline: 1.1375x; 1.0119x over previous
//
#include <hip/hip_runtime.h>
#include <hip/hip_bf16.h>

// ---------------------------------------------------------------------------
// Round 17: champion structure (R13/R16) with the second proven-redundant
// barrier removed. PV reads only (a) attn rows this wave itself wrote (DS
// in-order within wave) and (b) vT rows already synced by barrier (4).
// Barriers 7 -> 6. Everything else identical to the 275us champion.
//   x:(2,1024,64,512) f32  w:(1536,512) f32  pb:(8,64,64) f32  mk:(2,) bool
// ---------------------------------------------------------------------------

typedef __attribute__((ext_vector_type(4))) float f32x4;
typedef __attribute__((ext_vector_type(8))) short s16x8;

#define DIM 512

__device__ __forceinline__ short f2bf(float f) {
    __hip_bfloat16 h = __float2bfloat16(f);
    return __builtin_bit_cast(short, h);
}
__device__ __forceinline__ f32x4 ntld4(const float* p) {
    return __builtin_nontemporal_load((const f32x4*)p);
}
__device__ __forceinline__ void ntst4(float* p, f32x4 v) {
    __builtin_nontemporal_store(v, (f32x4*)p);
}
__device__ __forceinline__ s16x8 pack8(f32x4 a, f32x4 b) {
    s16x8 v;
    v[0] = f2bf(a[0]); v[1] = f2bf(a[1]); v[2] = f2bf(a[2]); v[3] = f2bf(a[3]);
    v[4] = f2bf(b[0]); v[5] = f2bf(b[1]); v[6] = f2bf(b[2]); v[7] = f2bf(b[3]);
    return v;
}
__device__ __forceinline__ int xaddr(int row, int kb) {   // 64x512 bf16, 1KiB rows
    return (row << 10) + (kb ^ ((row & 7) << 4));
}
__device__ __forceinline__ int taddr(int row, int kb) {   // 64x64 bf16, 128B rows
    return (row << 7) + (kb ^ ((row & 7) << 4));
}

// W pre-swizzle: frag chunk idx = (rowblk*16 + ks)*64 + lane -> one 1 KiB
// contiguous read per wave-fragment. q-scale (1/8) folded into Wq rows.
__global__ void conv_w(const float* __restrict__ w, unsigned short* __restrict__ wb) {
    int gid  = blockIdx.x * 256 + threadIdx.x;       // 0 .. 98303
    int lane = gid & 63;
    int ks   = (gid >> 6) & 15;
    int rowblk = gid >> 10;
    int row = rowblk * 16 + (lane & 15);
    int col = ks * 32 + (lane >> 4) * 8;
    const float* p = w + (size_t)row * DIM + col;
    f32x4 a = *(const f32x4*)p;
    f32x4 b = *(const f32x4*)(p + 4);
    float sc = (row < 512) ? 0.125f : 1.0f;
    a *= sc; b *= sc;
    *(s16x8*)(wb + (size_t)gid * 8) = pack8(a, b);
}

template<int WB16>
__device__ __forceinline__ s16x8 wfragL(const unsigned short* __restrict__ wb,
                                        const float* __restrict__ w,
                                        int rowblk, int ks, int lane) {
    if constexpr (WB16) {
        return *(const s16x8*)(wb + ((size_t)(rowblk * 16 + ks) * 64 + lane) * 8);
    } else {
        int row = rowblk * 16 + (lane & 15);
        int col = ks * 32 + (lane >> 4) * 8;
        const float* p = w + (size_t)row * DIM + col;
        f32x4 u0 = *(const f32x4*)p;
        f32x4 u1 = *(const f32x4*)(p + 4);
        float sc = (row < 512) ? 0.125f : 1.0f;
        u0 *= sc; u1 *= sc;
        return pack8(u0, u1);
    }
}

__device__ __forceinline__ bool decode_mask(const unsigned int* mk, int b) {
    unsigned int m0 = mk[0], m1 = mk[1];
    if (m0 <= 1u && m1 <= 1u) return ((b == 0) ? m0 : m1) != 0u;
    return ((const unsigned char*)mk)[b] != 0;
}

#define MFB(a, b, cc) __builtin_amdgcn_mfma_f32_16x16x32_bf16(a, b, cc, 0, 0, 0)

// X fragment reads (4 token-row tiles at K-slice ks) from region A (= smem)
#define XF(ks)                                                               \
    s16x8 af0 = *(const s16x8*)(smem + xaddr(c,      (ks) * 64 + g * 16));   \
    s16x8 af1 = *(const s16x8*)(smem + xaddr(16 + c, (ks) * 64 + g * 16));   \
    s16x8 af2 = *(const s16x8*)(smem + xaddr(32 + c, (ks) * 64 + g * 16));   \
    s16x8 af3 = *(const s16x8*)(smem + xaddr(48 + c, (ks) * 64 + g * 16));

template<int WB16>
__global__ __launch_bounds__(1024, 4)
void attn_merged(const float* __restrict__ x,
                 const float* __restrict__ w,
                 const unsigned short* __restrict__ wb,
                 const float* __restrict__ pb,
                 const unsigned int* __restrict__ mk,
                 float* __restrict__ out)
{
    extern __shared__ char smem[];
    const int tid  = threadIdx.x;
    const int lane = tid & 63;
    const int wave = tid >> 6;          // 0..15
    const int g    = lane >> 4;
    const int c    = lane & 15;
    const int hp   = wave >> 1;         // head
    const int hw2  = wave & 1;          // dh-half (proj) / token-half (attn)
    const int site = blockIdx.x;
    const bool focused = decode_mask(mk, site >> 10);
    const float* xblk   = x   + (size_t)site * (64 * DIM);
    float*       outblk = out + (size_t)site * (64 * DIM);
    const f32x4 zf = {0.f, 0.f, 0.f, 0.f};

    // ---- stage X: conflict-free (16-lane groups write 256B contiguous) ----
    {
        const int row = tid >> 4, c16 = tid & 15;
        const float* gp = xblk + row * DIM;
        #pragma unroll
        for (int j = 0; j < 4; ++j) {
            f32x4 a = ntld4(gp + j * 128 + c16 * 8);
            f32x4 b = ntld4(gp + j * 128 + c16 * 8 + 4);
            *(s16x8*)(smem + xaddr(row, j * 256 + c16 * 16)) = pack8(a, b);
        }
    }
    __syncthreads();                                         // (1) X ready

    if (focused) {
        // ---------- out = v = X . Wv^T (eye mask => attn = I) ----------
        const int RB = 64 + hp * 4 + 2 * hw2;
        f32x4 va[2][4];
        #pragma unroll
        for (int i = 0; i < 2; ++i)
            #pragma unroll
            for (int j = 0; j < 4; ++j) va[i][j] = zf;
        #pragma unroll 4
        for (int ks = 0; ks < 16; ++ks) {
            s16x8 wv0 = wfragL<WB16>(wb, w, RB,     ks, lane);
            s16x8 wv1 = wfragL<WB16>(wb, w, RB + 1, ks, lane);
            XF(ks)
            va[0][0]=MFB(wv0,af0,va[0][0]); va[0][1]=MFB(wv0,af1,va[0][1]);
            va[0][2]=MFB(wv0,af2,va[0][2]); va[0][3]=MFB(wv0,af3,va[0][3]);
            va[1][0]=MFB(wv1,af0,va[1][0]); va[1][1]=MFB(wv1,af1,va[1][1]);
            va[1][2]=MFB(wv1,af2,va[1][2]); va[1][3]=MFB(wv1,af3,va[1][3]);
        }
        // staged linear epilogue, two 32-row halves in region B
        char* stg = smem + 65536;
        #pragma unroll
        for (int h2 = 0; h2 < 2; ++h2) {
            #pragma unroll
            for (int sub = 0; sub < 2; ++sub)
                #pragma unroll
                for (int tn = 0; tn < 2; ++tn) {
                    int rl   = tn * 16 + c;                  // local token row
                    int colb = hp * 256 + hw2 * 128 + sub * 64 + g * 16;
                    *(f32x4*)(stg + rl * 2048 + (colb ^ ((rl & 7) << 4))) =
                        va[sub][h2 * 2 + tn];
                }
            __syncthreads();
            #pragma unroll
            for (int i = 0; i < 4; ++i) {
                int lin = i * 16384 + tid * 16;
                int rl = lin >> 11, off = lin & 2047;
                f32x4 v = *(const f32x4*)(stg + rl * 2048 + (off ^ ((rl & 7) << 4)));
                ntst4((float*)((char*)outblk + h2 * 65536 + lin), v);
            }
            if (h2 == 0) __syncthreads();
        }
        return;
    }

    // ===================== full-attention path =====================
    char* slotA = smem + hp * 8192;             // (X) -> k -> attn
    char* slotB = smem + 65536 + hp * 8192;     // q -> vT
    const int RQ = hp * 4 + 2 * hw2;
    const int RK = 32 + hp * 4 + 2 * hw2;

    // ---- Q pass (acc 32 regs) -> q tile straight to slotB ----
    {
        f32x4 acc[4][2];
        #pragma unroll
        for (int t = 0; t < 4; ++t) { acc[t][0] = zf; acc[t][1] = zf; }
        #pragma unroll 4
        for (int ks = 0; ks < 16; ++ks) {
            s16x8 w0 = wfragL<WB16>(wb, w, RQ,     ks, lane);
            s16x8 w1 = wfragL<WB16>(wb, w, RQ + 1, ks, lane);
            XF(ks)
            acc[0][0]=MFB(af0,w0,acc[0][0]); acc[0][1]=MFB(af0,w1,acc[0][1]);
            acc[1][0]=MFB(af1,w0,acc[1][0]); acc[1][1]=MFB(af1,w1,acc[1][1]);
            acc[2][0]=MFB(af2,w0,acc[2][0]); acc[2][1]=MFB(af2,w1,acc[2][1]);
            acc[3][0]=MFB(af3,w0,acc[3][0]); acc[3][1]=MFB(af3,w1,acc[3][1]);
        }
        #pragma unroll
        for (int t = 0; t < 4; ++t)
            #pragma unroll
            for (int hc = 0; hc < 2; ++hc)
                #pragma unroll
                for (int rr = 0; rr < 4; ++rr) {
                    int row = t * 16 + g * 4 + rr;
                    int col = hw2 * 32 + hc * 16 + c;
                    *(short*)(slotB + (row << 7) + ((col * 2) ^ ((row & 7) << 4))) =
                        f2bf(acc[t][hc][rr]);
                }
    }

    // ---- K pass (acc 32 regs) -> packed kc (16 regs) ----
    s16x8 kc[4];
    {
        f32x4 acc[4][2];
        #pragma unroll
        for (int t = 0; t < 4; ++t) { acc[t][0] = zf; acc[t][1] = zf; }
        #pragma unroll 4
        for (int ks = 0; ks < 16; ++ks) {
            s16x8 w0 = wfragL<WB16>(wb, w, RK,     ks, lane);
            s16x8 w1 = wfragL<WB16>(wb, w, RK + 1, ks, lane);
            XF(ks)
            acc[0][0]=MFB(af0,w0,acc[0][0]); acc[0][1]=MFB(af0,w1,acc[0][1]);
            acc[1][0]=MFB(af1,w0,acc[1][0]); acc[1][1]=MFB(af1,w1,acc[1][1]);
            acc[2][0]=MFB(af2,w0,acc[2][0]); acc[2][1]=MFB(af2,w1,acc[2][1]);
            acc[3][0]=MFB(af3,w0,acc[3][0]); acc[3][1]=MFB(af3,w1,acc[3][1]);
        }
        #pragma unroll
        for (int t = 0; t < 4; ++t) kc[t] = pack8(acc[t][0], acc[t][1]);
    }

    // ---- V pass as vT, two 1-rowblk sub-passes (acc 16 regs) ----
    s16x8 vc[4];
    #pragma unroll
    for (int sub = 0; sub < 2; ++sub) {
        const int RB = 64 + hp * 4 + 2 * hw2 + sub;
        f32x4 a0 = zf, a1 = zf, a2 = zf, a3 = zf;
        #pragma unroll 4
        for (int ks = 0; ks < 16; ++ks) {
            s16x8 wv = wfragL<WB16>(wb, w, RB, ks, lane);
            XF(ks)
            a0 = MFB(wv, af0, a0); a1 = MFB(wv, af1, a1);
            a2 = MFB(wv, af2, a2); a3 = MFB(wv, af3, a3);
        }
        vc[sub * 2]     = pack8(a0, a1);
        vc[sub * 2 + 1] = pack8(a2, a3);
    }

    __syncthreads();                                         // (2) X dead -> slots

    // ---- k -> slotA ----
    #pragma unroll
    for (int t = 0; t < 4; ++t)
        #pragma unroll
        for (int hc = 0; hc < 2; ++hc)
            #pragma unroll
            for (int rr = 0; rr < 4; ++rr) {
                int row = t * 16 + g * 4 + rr;
                int col = hw2 * 32 + hc * 16 + c;
                *(short*)(slotA + (row << 7) + ((col * 2) ^ ((row & 7) << 4))) =
                    kc[t][hc * 4 + rr];
            }
    __syncthreads();                                         // (3) q,k visible

    // ---- pre-read q A-frags into registers (16 regs), then retire vT ----
    // No barrier: reads/writes touch the same rows from the SAME wave (DS ops
    // in-order within a wave); partner wave's rows are disjoint.
    s16x8 qf[2][2];
    #pragma unroll
    for (int ks2 = 0; ks2 < 2; ++ks2)
        #pragma unroll
        for (int tr2 = 0; tr2 < 2; ++tr2)
            qf[ks2][tr2] = *(const s16x8*)(slotB +
                taddr((2 * hw2 + tr2) * 16 + c, ks2 * 64 + g * 16));

    // vT -> slotB (own dh-half rows); vc dies here, before sim
    #pragma unroll
    for (int sub = 0; sub < 2; ++sub)
        #pragma unroll
        for (int t = 0; t < 4; ++t)
            #pragma unroll
            for (int rr = 0; rr < 4; ++rr) {
                int row = hw2 * 32 + sub * 16 + g * 4 + rr;
                int col = t * 16 + c;
                *(short*)(slotB + (row << 7) + ((col * 2) ^ ((row & 7) << 4))) =
                    vc[sub * 2 + (t >> 1)][(t & 1) * 4 + rr];
            }

    // ---- sim = q . k^T (q from regs, k from slotA, sequenced) ----
    f32x4 sm[2][4];
    #pragma unroll
    for (int i = 0; i < 2; ++i)
        #pragma unroll
        for (int j = 0; j < 4; ++j) sm[i][j] = zf;
    #pragma unroll
    for (int ks2 = 0; ks2 < 2; ++ks2) {
        #pragma unroll
        for (int j = 0; j < 4; ++j) {
            s16x8 bk = *(const s16x8*)(slotA + taddr(j * 16 + c, ks2 * 64 + g * 16));
            sm[0][j] = MFB(qf[ks2][0], bk, sm[0][j]);
            sm[1][j] = MFB(qf[ks2][1], bk, sm[1][j]);
        }
    }

    // ---- bias + softmax ----
    const float* pbh = pb + hp * 4096;
    #pragma unroll
    for (int tr = 0; tr < 2; ++tr) {
        #pragma unroll
        for (int rr = 0; rr < 4; ++rr) {
            const int i = 32 * hw2 + tr * 16 + g * 4 + rr;
            float v0 = sm[tr][0][rr] + pbh[i * 64 +  0 + c];
            float v1 = sm[tr][1][rr] + pbh[i * 64 + 16 + c];
            float v2 = sm[tr][2][rr] + pbh[i * 64 + 32 + c];
            float v3 = sm[tr][3][rr] + pbh[i * 64 + 48 + c];
            float mx = fmaxf(fmaxf(v0, v1), fmaxf(v2, v3));
            mx = fmaxf(mx, __shfl_xor(mx, 1));
            mx = fmaxf(mx, __shfl_xor(mx, 2));
            mx = fmaxf(mx, __shfl_xor(mx, 4));
            mx = fmaxf(mx, __shfl_xor(mx, 8));
            float p0 = __expf(v0 - mx);
            float p1 = __expf(v1 - mx);
            float p2 = __expf(v2 - mx);
            float p3 = __expf(v3 - mx);
            float ssum = p0 + p1 + p2 + p3;
            ssum += __shfl_xor(ssum, 1);
            ssum += __shfl_xor(ssum, 2);
            ssum += __shfl_xor(ssum, 4);
            ssum += __shfl_xor(ssum, 8);
            float rinv = 1.0f / ssum;
            sm[tr][0][rr] = p0 * rinv; sm[tr][1][rr] = p1 * rinv;
            sm[tr][2][rr] = p2 * rinv; sm[tr][3][rr] = p3 * rinv;
        }
    }
    __syncthreads();                                         // (4) k reads done

    // ---- attn -> slotA (own token-half rows); PV reads ONLY these own rows
    // plus vT (synced at (4)) -> no barrier needed before PV.
    #pragma unroll
    for (int tr = 0; tr < 2; ++tr)
        #pragma unroll
        for (int tc = 0; tc < 4; ++tc)
            #pragma unroll
            for (int rr = 0; rr < 4; ++rr) {
                int row = 32 * hw2 + tr * 16 + g * 4 + rr;
                int col = tc * 16 + c;
                *(short*)(slotA + (row << 7) + ((col * 2) ^ ((row & 7) << 4))) =
                    f2bf(sm[tr][tc][rr]);
            }

    // ---- PV: oT = vT . attn^T (token-split cols), frags sequenced ----
    f32x4 ot[4][2];
    #pragma unroll
    for (int i = 0; i < 4; ++i) { ot[i][0] = zf; ot[i][1] = zf; }
    #pragma unroll
    for (int ks2 = 0; ks2 < 2; ++ks2) {
        s16x8 ba0 = *(const s16x8*)(slotA + taddr((2 * hw2 + 0) * 16 + c, ks2 * 64 + g * 16));
        s16x8 ba1 = *(const s16x8*)(slotA + taddr((2 * hw2 + 1) * 16 + c, ks2 * 64 + g * 16));
        #pragma unroll
        for (int i = 0; i < 4; ++i) {
            s16x8 av = *(const s16x8*)(slotB + taddr(i * 16 + c, ks2 * 64 + g * 16));
            ot[i][0] = MFB(av, ba0, ot[i][0]);
            ot[i][1] = MFB(av, ba1, ot[i][1]);
        }
    }
    __syncthreads();                                         // (6) slots dead

    // ---- staged linear epilogue over full 128 KiB ----
    #pragma unroll
    for (int i = 0; i < 4; ++i)
        #pragma unroll
        for (int j = 0; j < 2; ++j) {
            int rl   = 32 * hw2 + j * 16 + c;                // token row
            int colb = hp * 256 + i * 64 + g * 16;           // dh byte offset
            *(f32x4*)(smem + rl * 2048 + (colb ^ ((rl & 7) << 4))) = ot[i][j];
        }
    __syncthreads();                                         // (7)
    #pragma unroll
    for (int i = 0; i < 8; ++i) {
        int lin = i * 16384 + tid * 16;
        int rl = lin >> 11, off = lin & 2047;
        f32x4 v = *(const f32x4*)(smem + rl * 2048 + (off ^ ((rl & 7) << 4)));
        ntst4((float*)((char*)outblk + lin), v);
    }
}

extern "C" void kernel_launch(void* const* d_in, const int* in_sizes, int n_in,
                              void* d_out, int out_size, void* d_ws, size_t ws_size,
                              hipStream_t stream)
{
    const float* x  = (const float*)d_in[0];
    const float* w  = (const float*)d_in[1];
    const float* pb = (const float*)d_in[2];
    const unsigned int* mk = (const unsigned int*)d_in[3];
    float* out = (float*)d_out;

    const int LDS = 131072;
    const size_t wbytes = (size_t)1536 * 512 * sizeof(unsigned short);

    if (ws_size >= wbytes) {
        unsigned short* wbp = (unsigned short*)d_ws;
        conv_w<<<dim3(384), dim3(256), 0, stream>>>(w, wbp);
        hipFuncSetAttribute(reinterpret_cast<const void*>(&attn_merged<1>),
                            hipFuncAttributeMaxDynamicSharedMemorySize, LDS);
        attn_merged<1><<<dim3(2048), dim3(1024), LDS, stream>>>(x, w, wbp, pb, mk, out);
    } else {
        hipFuncSetAttribute(reinterpret_cast<const void*>(&attn_merged<0>),
                            hipFuncAttributeMaxDynamicSharedMemorySize, LDS);
        attn_merged<0><<<dim3(2048), dim3(1024), LDS, stream>>>(x, w, nullptr, pb, mk, out);
    }
}

// Round 18
// 262.125 us; speedup vs baseline: 1.1919x; 1.0479x over previous
//
#include <hip/hip_runtime.h>
#include <hip/hip_bf16.h>

// ---------------------------------------------------------------------------
// Round 18: R17 champion + T5 s_setprio(1) around MFMA clusters (proj K-steps,
// sim, PV). Waves desync between barriers (1)-(2) -> role diversity exists;
// MFMA-ready waves get scheduler priority over load-issuing waves.
//   x:(2,1024,64,512) f32  w:(1536,512) f32  pb:(8,64,64) f32  mk:(2,) bool
// ---------------------------------------------------------------------------

typedef __attribute__((ext_vector_type(4))) float f32x4;
typedef __attribute__((ext_vector_type(8))) short s16x8;

#define DIM 512

__device__ __forceinline__ short f2bf(float f) {
    __hip_bfloat16 h = __float2bfloat16(f);
    return __builtin_bit_cast(short, h);
}
__device__ __forceinline__ f32x4 ntld4(const float* p) {
    return __builtin_nontemporal_load((const f32x4*)p);
}
__device__ __forceinline__ void ntst4(float* p, f32x4 v) {
    __builtin_nontemporal_store(v, (f32x4*)p);
}
__device__ __forceinline__ s16x8 pack8(f32x4 a, f32x4 b) {
    s16x8 v;
    v[0] = f2bf(a[0]); v[1] = f2bf(a[1]); v[2] = f2bf(a[2]); v[3] = f2bf(a[3]);
    v[4] = f2bf(b[0]); v[5] = f2bf(b[1]); v[6] = f2bf(b[2]); v[7] = f2bf(b[3]);
    return v;
}
__device__ __forceinline__ int xaddr(int row, int kb) {   // 64x512 bf16, 1KiB rows
    return (row << 10) + (kb ^ ((row & 7) << 4));
}
__device__ __forceinline__ int taddr(int row, int kb) {   // 64x64 bf16, 128B rows
    return (row << 7) + (kb ^ ((row & 7) << 4));
}

// W pre-swizzle: frag chunk idx = (rowblk*16 + ks)*64 + lane -> one 1 KiB
// contiguous read per wave-fragment. q-scale (1/8) folded into Wq rows.
__global__ void conv_w(const float* __restrict__ w, unsigned short* __restrict__ wb) {
    int gid  = blockIdx.x * 256 + threadIdx.x;       // 0 .. 98303
    int lane = gid & 63;
    int ks   = (gid >> 6) & 15;
    int rowblk = gid >> 10;
    int row = rowblk * 16 + (lane & 15);
    int col = ks * 32 + (lane >> 4) * 8;
    const float* p = w + (size_t)row * DIM + col;
    f32x4 a = *(const f32x4*)p;
    f32x4 b = *(const f32x4*)(p + 4);
    float sc = (row < 512) ? 0.125f : 1.0f;
    a *= sc; b *= sc;
    *(s16x8*)(wb + (size_t)gid * 8) = pack8(a, b);
}

template<int WB16>
__device__ __forceinline__ s16x8 wfragL(const unsigned short* __restrict__ wb,
                                        const float* __restrict__ w,
                                        int rowblk, int ks, int lane) {
    if constexpr (WB16) {
        return *(const s16x8*)(wb + ((size_t)(rowblk * 16 + ks) * 64 + lane) * 8);
    } else {
        int row = rowblk * 16 + (lane & 15);
        int col = ks * 32 + (lane >> 4) * 8;
        const float* p = w + (size_t)row * DIM + col;
        f32x4 u0 = *(const f32x4*)p;
        f32x4 u1 = *(const f32x4*)(p + 4);
        float sc = (row < 512) ? 0.125f : 1.0f;
        u0 *= sc; u1 *= sc;
        return pack8(u0, u1);
    }
}

__device__ __forceinline__ bool decode_mask(const unsigned int* mk, int b) {
    unsigned int m0 = mk[0], m1 = mk[1];
    if (m0 <= 1u && m1 <= 1u) return ((b == 0) ? m0 : m1) != 0u;
    return ((const unsigned char*)mk)[b] != 0;
}

#define MFB(a, b, cc) __builtin_amdgcn_mfma_f32_16x16x32_bf16(a, b, cc, 0, 0, 0)
#define PRIO1 __builtin_amdgcn_s_setprio(1);
#define PRIO0 __builtin_amdgcn_s_setprio(0);

// X fragment reads (4 token-row tiles at K-slice ks) from region A (= smem)
#define XF(ks)                                                               \
    s16x8 af0 = *(const s16x8*)(smem + xaddr(c,      (ks) * 64 + g * 16));   \
    s16x8 af1 = *(const s16x8*)(smem + xaddr(16 + c, (ks) * 64 + g * 16));   \
    s16x8 af2 = *(const s16x8*)(smem + xaddr(32 + c, (ks) * 64 + g * 16));   \
    s16x8 af3 = *(const s16x8*)(smem + xaddr(48 + c, (ks) * 64 + g * 16));

template<int WB16>
__global__ __launch_bounds__(1024, 4)
void attn_merged(const float* __restrict__ x,
                 const float* __restrict__ w,
                 const unsigned short* __restrict__ wb,
                 const float* __restrict__ pb,
                 const unsigned int* __restrict__ mk,
                 float* __restrict__ out)
{
    extern __shared__ char smem[];
    const int tid  = threadIdx.x;
    const int lane = tid & 63;
    const int wave = tid >> 6;          // 0..15
    const int g    = lane >> 4;
    const int c    = lane & 15;
    const int hp   = wave >> 1;         // head
    const int hw2  = wave & 1;          // dh-half (proj) / token-half (attn)
    const int site = blockIdx.x;
    const bool focused = decode_mask(mk, site >> 10);
    const float* xblk   = x   + (size_t)site * (64 * DIM);
    float*       outblk = out + (size_t)site * (64 * DIM);
    const f32x4 zf = {0.f, 0.f, 0.f, 0.f};

    // ---- stage X: conflict-free (16-lane groups write 256B contiguous) ----
    {
        const int row = tid >> 4, c16 = tid & 15;
        const float* gp = xblk + row * DIM;
        #pragma unroll
        for (int j = 0; j < 4; ++j) {
            f32x4 a = ntld4(gp + j * 128 + c16 * 8);
            f32x4 b = ntld4(gp + j * 128 + c16 * 8 + 4);
            *(s16x8*)(smem + xaddr(row, j * 256 + c16 * 16)) = pack8(a, b);
        }
    }
    __syncthreads();                                         // (1) X ready

    if (focused) {
        // ---------- out = v = X . Wv^T (eye mask => attn = I) ----------
        const int RB = 64 + hp * 4 + 2 * hw2;
        f32x4 va[2][4];
        #pragma unroll
        for (int i = 0; i < 2; ++i)
            #pragma unroll
            for (int j = 0; j < 4; ++j) va[i][j] = zf;
        #pragma unroll 4
        for (int ks = 0; ks < 16; ++ks) {
            s16x8 wv0 = wfragL<WB16>(wb, w, RB,     ks, lane);
            s16x8 wv1 = wfragL<WB16>(wb, w, RB + 1, ks, lane);
            XF(ks)
            PRIO1
            va[0][0]=MFB(wv0,af0,va[0][0]); va[0][1]=MFB(wv0,af1,va[0][1]);
            va[0][2]=MFB(wv0,af2,va[0][2]); va[0][3]=MFB(wv0,af3,va[0][3]);
            va[1][0]=MFB(wv1,af0,va[1][0]); va[1][1]=MFB(wv1,af1,va[1][1]);
            va[1][2]=MFB(wv1,af2,va[1][2]); va[1][3]=MFB(wv1,af3,va[1][3]);
            PRIO0
        }
        // staged linear epilogue, two 32-row halves in region B
        char* stg = smem + 65536;
        #pragma unroll
        for (int h2 = 0; h2 < 2; ++h2) {
            #pragma unroll
            for (int sub = 0; sub < 2; ++sub)
                #pragma unroll
                for (int tn = 0; tn < 2; ++tn) {
                    int rl   = tn * 16 + c;                  // local token row
                    int colb = hp * 256 + hw2 * 128 + sub * 64 + g * 16;
                    *(f32x4*)(stg + rl * 2048 + (colb ^ ((rl & 7) << 4))) =
                        va[sub][h2 * 2 + tn];
                }
            __syncthreads();
            #pragma unroll
            for (int i = 0; i < 4; ++i) {
                int lin = i * 16384 + tid * 16;
                int rl = lin >> 11, off = lin & 2047;
                f32x4 v = *(const f32x4*)(stg + rl * 2048 + (off ^ ((rl & 7) << 4)));
                ntst4((float*)((char*)outblk + h2 * 65536 + lin), v);
            }
            if (h2 == 0) __syncthreads();
        }
        return;
    }

    // ===================== full-attention path =====================
    char* slotA = smem + hp * 8192;             // (X) -> k -> attn
    char* slotB = smem + 65536 + hp * 8192;     // q -> vT
    const int RQ = hp * 4 + 2 * hw2;
    const int RK = 32 + hp * 4 + 2 * hw2;

    // ---- Q pass (acc 32 regs) -> q tile straight to slotB ----
    {
        f32x4 acc[4][2];
        #pragma unroll
        for (int t = 0; t < 4; ++t) { acc[t][0] = zf; acc[t][1] = zf; }
        #pragma unroll 4
        for (int ks = 0; ks < 16; ++ks) {
            s16x8 w0 = wfragL<WB16>(wb, w, RQ,     ks, lane);
            s16x8 w1 = wfragL<WB16>(wb, w, RQ + 1, ks, lane);
            XF(ks)
            PRIO1
            acc[0][0]=MFB(af0,w0,acc[0][0]); acc[0][1]=MFB(af0,w1,acc[0][1]);
            acc[1][0]=MFB(af1,w0,acc[1][0]); acc[1][1]=MFB(af1,w1,acc[1][1]);
            acc[2][0]=MFB(af2,w0,acc[2][0]); acc[2][1]=MFB(af2,w1,acc[2][1]);
            acc[3][0]=MFB(af3,w0,acc[3][0]); acc[3][1]=MFB(af3,w1,acc[3][1]);
            PRIO0
        }
        #pragma unroll
        for (int t = 0; t < 4; ++t)
            #pragma unroll
            for (int hc = 0; hc < 2; ++hc)
                #pragma unroll
                for (int rr = 0; rr < 4; ++rr) {
                    int row = t * 16 + g * 4 + rr;
                    int col = hw2 * 32 + hc * 16 + c;
                    *(short*)(slotB + (row << 7) + ((col * 2) ^ ((row & 7) << 4))) =
                        f2bf(acc[t][hc][rr]);
                }
    }

    // ---- K pass (acc 32 regs) -> packed kc (16 regs) ----
    s16x8 kc[4];
    {
        f32x4 acc[4][2];
        #pragma unroll
        for (int t = 0; t < 4; ++t) { acc[t][0] = zf; acc[t][1] = zf; }
        #pragma unroll 4
        for (int ks = 0; ks < 16; ++ks) {
            s16x8 w0 = wfragL<WB16>(wb, w, RK,     ks, lane);
            s16x8 w1 = wfragL<WB16>(wb, w, RK + 1, ks, lane);
            XF(ks)
            PRIO1
            acc[0][0]=MFB(af0,w0,acc[0][0]); acc[0][1]=MFB(af0,w1,acc[0][1]);
            acc[1][0]=MFB(af1,w0,acc[1][0]); acc[1][1]=MFB(af1,w1,acc[1][1]);
            acc[2][0]=MFB(af2,w0,acc[2][0]); acc[2][1]=MFB(af2,w1,acc[2][1]);
            acc[3][0]=MFB(af3,w0,acc[3][0]); acc[3][1]=MFB(af3,w1,acc[3][1]);
            PRIO0
        }
        #pragma unroll
        for (int t = 0; t < 4; ++t) kc[t] = pack8(acc[t][0], acc[t][1]);
    }

    // ---- V pass as vT, two 1-rowblk sub-passes (acc 16 regs) ----
    s16x8 vc[4];
    #pragma unroll
    for (int sub = 0; sub < 2; ++sub) {
        const int RB = 64 + hp * 4 + 2 * hw2 + sub;
        f32x4 a0 = zf, a1 = zf, a2 = zf, a3 = zf;
        #pragma unroll 4
        for (int ks = 0; ks < 16; ++ks) {
            s16x8 wv = wfragL<WB16>(wb, w, RB, ks, lane);
            XF(ks)
            PRIO1
            a0 = MFB(wv, af0, a0); a1 = MFB(wv, af1, a1);
            a2 = MFB(wv, af2, a2); a3 = MFB(wv, af3, a3);
            PRIO0
        }
        vc[sub * 2]     = pack8(a0, a1);
        vc[sub * 2 + 1] = pack8(a2, a3);
    }

    __syncthreads();                                         // (2) X dead -> slots

    // ---- k -> slotA ----
    #pragma unroll
    for (int t = 0; t < 4; ++t)
        #pragma unroll
        for (int hc = 0; hc < 2; ++hc)
            #pragma unroll
            for (int rr = 0; rr < 4; ++rr) {
                int row = t * 16 + g * 4 + rr;
                int col = hw2 * 32 + hc * 16 + c;
                *(short*)(slotA + (row << 7) + ((col * 2) ^ ((row & 7) << 4))) =
                    kc[t][hc * 4 + rr];
            }
    __syncthreads();                                         // (3) q,k visible

    // ---- pre-read q A-frags into registers (16 regs), then retire vT ----
    s16x8 qf[2][2];
    #pragma unroll
    for (int ks2 = 0; ks2 < 2; ++ks2)
        #pragma unroll
        for (int tr2 = 0; tr2 < 2; ++tr2)
            qf[ks2][tr2] = *(const s16x8*)(slotB +
                taddr((2 * hw2 + tr2) * 16 + c, ks2 * 64 + g * 16));

    // vT -> slotB (own dh-half rows); vc dies here, before sim
    #pragma unroll
    for (int sub = 0; sub < 2; ++sub)
        #pragma unroll
        for (int t = 0; t < 4; ++t)
            #pragma unroll
            for (int rr = 0; rr < 4; ++rr) {
                int row = hw2 * 32 + sub * 16 + g * 4 + rr;
                int col = t * 16 + c;
                *(short*)(slotB + (row << 7) + ((col * 2) ^ ((row & 7) << 4))) =
                    vc[sub * 2 + (t >> 1)][(t & 1) * 4 + rr];
            }

    // ---- sim = q . k^T (q from regs, k from slotA, sequenced) ----
    f32x4 sm[2][4];
    #pragma unroll
    for (int i = 0; i < 2; ++i)
        #pragma unroll
        for (int j = 0; j < 4; ++j) sm[i][j] = zf;
    #pragma unroll
    for (int ks2 = 0; ks2 < 2; ++ks2) {
        #pragma unroll
        for (int j = 0; j < 4; ++j) {
            s16x8 bk = *(const s16x8*)(slotA + taddr(j * 16 + c, ks2 * 64 + g * 16));
            PRIO1
            sm[0][j] = MFB(qf[ks2][0], bk, sm[0][j]);
            sm[1][j] = MFB(qf[ks2][1], bk, sm[1][j]);
            PRIO0
        }
    }

    // ---- bias + softmax ----
    const float* pbh = pb + hp * 4096;
    #pragma unroll
    for (int tr = 0; tr < 2; ++tr) {
        #pragma unroll
        for (int rr = 0; rr < 4; ++rr) {
            const int i = 32 * hw2 + tr * 16 + g * 4 + rr;
            float v0 = sm[tr][0][rr] + pbh[i * 64 +  0 + c];
            float v1 = sm[tr][1][rr] + pbh[i * 64 + 16 + c];
            float v2 = sm[tr][2][rr] + pbh[i * 64 + 32 + c];
            float v3 = sm[tr][3][rr] + pbh[i * 64 + 48 + c];
            float mx = fmaxf(fmaxf(v0, v1), fmaxf(v2, v3));
            mx = fmaxf(mx, __shfl_xor(mx, 1));
            mx = fmaxf(mx, __shfl_xor(mx, 2));
            mx = fmaxf(mx, __shfl_xor(mx, 4));
            mx = fmaxf(mx, __shfl_xor(mx, 8));
            float p0 = __expf(v0 - mx);
            float p1 = __expf(v1 - mx);
            float p2 = __expf(v2 - mx);
            float p3 = __expf(v3 - mx);
            float ssum = p0 + p1 + p2 + p3;
            ssum += __shfl_xor(ssum, 1);
            ssum += __shfl_xor(ssum, 2);
            ssum += __shfl_xor(ssum, 4);
            ssum += __shfl_xor(ssum, 8);
            float rinv = 1.0f / ssum;
            sm[tr][0][rr] = p0 * rinv; sm[tr][1][rr] = p1 * rinv;
            sm[tr][2][rr] = p2 * rinv; sm[tr][3][rr] = p3 * rinv;
        }
    }
    __syncthreads();                                         // (4) k reads done

    // ---- attn -> slotA (own token-half rows); PV reads only own rows + vT
    #pragma unroll
    for (int tr = 0; tr < 2; ++tr)
        #pragma unroll
        for (int tc = 0; tc < 4; ++tc)
            #pragma unroll
            for (int rr = 0; rr < 4; ++rr) {
                int row = 32 * hw2 + tr * 16 + g * 4 + rr;
                int col = tc * 16 + c;
                *(short*)(slotA + (row << 7) + ((col * 2) ^ ((row & 7) << 4))) =
                    f2bf(sm[tr][tc][rr]);
            }

    // ---- PV: oT = vT . attn^T (token-split cols), frags sequenced ----
    f32x4 ot[4][2];
    #pragma unroll
    for (int i = 0; i < 4; ++i) { ot[i][0] = zf; ot[i][1] = zf; }
    #pragma unroll
    for (int ks2 = 0; ks2 < 2; ++ks2) {
        s16x8 ba0 = *(const s16x8*)(slotA + taddr((2 * hw2 + 0) * 16 + c, ks2 * 64 + g * 16));
        s16x8 ba1 = *(const s16x8*)(slotA + taddr((2 * hw2 + 1) * 16 + c, ks2 * 64 + g * 16));
        #pragma unroll
        for (int i = 0; i < 4; ++i) {
            s16x8 av = *(const s16x8*)(slotB + taddr(i * 16 + c, ks2 * 64 + g * 16));
            PRIO1
            ot[i][0] = MFB(av, ba0, ot[i][0]);
            ot[i][1] = MFB(av, ba1, ot[i][1]);
            PRIO0
        }
    }
    __syncthreads();                                         // (6) slots dead

    // ---- staged linear epilogue over full 128 KiB ----
    #pragma unroll
    for (int i = 0; i < 4; ++i)
        #pragma unroll
        for (int j = 0; j < 2; ++j) {
            int rl   = 32 * hw2 + j * 16 + c;                // token row
            int colb = hp * 256 + i * 64 + g * 16;           // dh byte offset
            *(f32x4*)(smem + rl * 2048 + (colb ^ ((rl & 7) << 4))) = ot[i][j];
        }
    __syncthreads();                                         // (7)
    #pragma unroll
    for (int i = 0; i < 8; ++i) {
        int lin = i * 16384 + tid * 16;
        int rl = lin >> 11, off = lin & 2047;
        f32x4 v = *(const f32x4*)(smem + rl * 2048 + (off ^ ((rl & 7) << 4)));
        ntst4((float*)((char*)outblk + lin), v);
    }
}

extern "C" void kernel_launch(void* const* d_in, const int* in_sizes, int n_in,
                              void* d_out, int out_size, void* d_ws, size_t ws_size,
                              hipStream_t stream)
{
    const float* x  = (const float*)d_in[0];
    const float* w  = (const float*)d_in[1];
    const float* pb = (const float*)d_in[2];
    const unsigned int* mk = (const unsigned int*)d_in[3];
    float* out = (float*)d_out;

    const int LDS = 131072;
    const size_t wbytes = (size_t)1536 * 512 * sizeof(unsigned short);

    if (ws_size >= wbytes) {
        unsigned short* wbp = (unsigned short*)d_ws;
        conv_w<<<dim3(384), dim3(256), 0, stream>>>(w, wbp);
        hipFuncSetAttribute(reinterpret_cast<const void*>(&attn_merged<1>),
                            hipFuncAttributeMaxDynamicSharedMemorySize, LDS);
        attn_merged<1><<<dim3(2048), dim3(1024), LDS, stream>>>(x, w, wbp, pb, mk, out);
    } else {
        hipFuncSetAttribute(reinterpret_cast<const void*>(&attn_merged<0>),
                            hipFuncAttributeMaxDynamicSharedMemorySize, LDS);
        attn_merged<0><<<dim3(2048), dim3(1024), LDS, stream>>>(x, w, nullptr, pb, mk, out);
    }
}